// Round 1
// 996.051 us; speedup vs baseline: 1.0583x; 1.0583x over previous
//
#include <hip/hip_runtime.h>
#include <hip/hip_bf16.h>
#include <stdint.h>
#include <math.h>

// Problem constants (fixed-shape problem)
#define BQ 4
#define NQ 4096
#define CQ 1024

// ws layout (bytes)
#define WS_CTR      0         // int c123 @0, c3f @4; int refCount[4] @16
#define WS_THRESH   64        // float[4]
#define WS_MASK     256       // uint8[BQ*NQ] = 16384  -> ends 16640
#define WS_REFIDX   17408     // int[BQ*NQ]  = 65536  -> ends 82944
#define WS_MAXV     82944     // float[BQ*NQ]= 65536  -> ends 148480
#define WS_INVN     148480    // double[BQ*NQ]=131072 -> ends 279552 (8-aligned)
#define WS_FNB      (4u << 20)             // bf16[BQ*NQ*CQ] = 32 MB
#define WS_NEED     (WS_FNB + (32u << 20) + (1u << 20))

typedef __bf16 bf16x8 __attribute__((ext_vector_type(8)));
typedef float floatx4 __attribute__((ext_vector_type(4)));

// ---------------------------------------------------------------------------
// K0a: detect mask dtype. Reads only first BQ*NQ bytes (safe under u8/i32/f32).
__global__ void k_detect(const uint8_t* mraw, int* ctr) {
    int c123 = 0, c3f = 0;
    for (int i = threadIdx.x; i < BQ * NQ; i += blockDim.x) {
        uint8_t v = mraw[i];
        int m4 = i & 3;
        if (m4 != 0 && v != 0) c123++;
        if (m4 == 3 && v == 0x3F) c3f++;
    }
    atomicAdd(&ctr[0], c123);
    atomicAdd(&ctr[1], c3f);
}

// K0b: canonicalize mask to uint8 0/1
__global__ void k_canon(const void* mraw, const int* ctr, uint8_t* maskc) {
    int i = blockIdx.x * blockDim.x + threadIdx.x;
    if (i >= BQ * NQ) return;
    int c123 = ctr[0], c3f = ctr[1];
    uint8_t v;
    if (c3f > 64) {
        v = (((const float*)mraw)[i] != 0.0f) ? 1 : 0;
    } else if (c123 == 0) {
        v = (((const int*)mraw)[i] != 0) ? 1 : 0;
    } else {
        v = (((const uint8_t*)mraw)[i] != 0) ? 1 : 0;
    }
    maskc[i] = v;
}

// K0c: compact ref-row indices per batch
__global__ void k_compact(const uint8_t* maskc, int* refCount, int* refIdx) {
    int b = blockIdx.x;
    for (int i = threadIdx.x; i < NQ; i += blockDim.x) {
        if (maskc[b * NQ + i]) {
            int p = atomicAdd(&refCount[b], 1);
            refIdx[b * NQ + p] = i;
        }
    }
}

// K1: fused row norm (f64) + bf16 normalized convert. One 128-thread block/row.
__global__ __launch_bounds__(128) void k_prep(const float* x, double* invn, __bf16* fnb) {
    int row = blockIdx.x;  // 0..BQ*NQ-1
    int t = threadIdx.x;
    const float4* xr = (const float4*)(x + (long long)row * CQ);
    float4 a = xr[t * 2 + 0];
    float4 c = xr[t * 2 + 1];
    double s = (double)a.x * a.x + (double)a.y * a.y + (double)a.z * a.z + (double)a.w * a.w
             + (double)c.x * c.x + (double)c.y * c.y + (double)c.z * c.z + (double)c.w * c.w;
    __shared__ double red[128];
    __shared__ double invs;
    red[t] = s;
    __syncthreads();
    for (int o = 64; o > 0; o >>= 1) {
        if (t < o) red[t] += red[t + o];
        __syncthreads();
    }
    if (t == 0) {
        double inv = 1.0 / fmax(sqrt(red[0]), 1e-12);
        invn[row] = inv;
        invs = inv;
    }
    __syncthreads();
    float ir = (float)invs;
    bf16x8 o8;
    o8[0] = (__bf16)(a.x * ir); o8[1] = (__bf16)(a.y * ir);
    o8[2] = (__bf16)(a.z * ir); o8[3] = (__bf16)(a.w * ir);
    o8[4] = (__bf16)(c.x * ir); o8[5] = (__bf16)(c.y * ir);
    o8[6] = (__bf16)(c.z * ir); o8[7] = (__bf16)(c.w * ir);
    *(bf16x8*)(fnb + (long long)row * CQ + t * 8) = o8;
}

// K2: fused mega-kernel. Block ids with id%3==2 run the f64 ref-row GEMM
// (f64 VALU pipe); the rest run the bf16 MFMA Gram GEMM (MFMA pipe).
// Interleaving 1-in-3 keeps every CU's pipes mixed (m114 co-scheduling);
// modulus 3 is coprime to 8 XCDs so both types land on every XCD.
//
// R1 changes vs previous session:
//  * SYMMETRY: Gram matrix is symmetric -> bf16 blocks compute only upper-
//    triangular tiles (rT <= cT): 528 tiles/batch * 4 = 2112 blocks (was 4096).
//    Off-diagonal blocks mirror-write the transposed tile; MFMA partial-sum
//    order is operand-symmetric so mirrored values are BIT-IDENTICAL to what
//    the (cT,rT) block would have produced (absmax unchanged).
//    Mirror store is float4-coalesced: acc[i][j] holds 4 consecutive rows at
//    one col -> transposed write = float4 at c*NQ+r0; lanes {l,l+16,l+32,l+48}
//    complete full 64B lines.
//  * LDS SWIZZLE (T2 / rule #21): [128][32] bf16 tile has 64B rows; unswizzled
//    ds_read_b128 across 16 rows alternated banks {0,16} = 8-way conflict
//    (3.3e7 conflict cycles measured). Keep LDS dest linear (global_load_lds
//    requires it), XOR-permute the GLOBAL source chunk, apply same XOR on the
//    read. swz(row)=((row>>1)&3)<<3 elems; both sides are lane-constant:
//    stage col ^= ((lane>>3)&3)<<3, read col ^= ((lane>>1)&3)<<3.
#define GRID_MEGA 6144  // 4096 bf16 slots (2112 active) + 2048 f64 blocks
__global__ __launch_bounds__(256) void k_mega(const __bf16* fnb, const float* x,
                                              const double* invn, const int* refCount,
                                              const int* refIdx, const uint8_t* maskc,
                                              float* sim, float* match) {
    __shared__ __align__(16) char smem[16384];
    const int t = threadIdx.x;
    const int id = blockIdx.x;

    if ((id % 3) == 2) {
        // ---------------- f64 ref-row GEMM: 32 ref rows x 64 cols, BK=32 ----
        const int fid = id / 3;            // 0..2047
        const int b = fid >> 9;
        const int rowT0 = (fid >> 6) & 7;
        const int colT = fid & 63;
        const int cnt = refCount[b];
        float* sAf = (float*)smem;                 // [32][36] f32 = 4608 B
        float* sBf = (float*)(smem + 4608);        // [32][68] f32 = 8704 B
        int* sRef  = (int*)(smem + 13312);         // [32]
        const float* xb = x + (long long)b * NQ * CQ;
        const int lrA = t >> 3, lkA = (t & 7) * 4;
        const int lrB = t >> 2, lkB = (t & 3) * 8;
        const int ty = t >> 4, tx = t & 15;
        for (int rowT = rowT0; rowT * 32 < cnt; rowT += 8) {  // grid-stride (cnt>256 safe)
            __syncthreads();
            if (t < 32) {
                int rg = rowT * 32 + t;
                sRef[t] = (rg < cnt) ? refIdx[b * NQ + rg] : refIdx[b * NQ];
            }
            __syncthreads();
            const int arow = sRef[lrA];
            const int brow = colT * 64 + lrB;
            double acc[2][4] = {};
            for (int k0 = 0; k0 < CQ; k0 += 32) {
                float4 av = *(const float4*)(xb + (long long)arow * CQ + k0 + lkA);
                float4 b0 = *(const float4*)(xb + (long long)brow * CQ + k0 + lkB);
                float4 b1 = *(const float4*)(xb + (long long)brow * CQ + k0 + lkB + 4);
                __syncthreads();
                sAf[(lkA + 0) * 36 + lrA] = av.x; sAf[(lkA + 1) * 36 + lrA] = av.y;
                sAf[(lkA + 2) * 36 + lrA] = av.z; sAf[(lkA + 3) * 36 + lrA] = av.w;
                sBf[(lkB + 0) * 68 + lrB] = b0.x; sBf[(lkB + 1) * 68 + lrB] = b0.y;
                sBf[(lkB + 2) * 68 + lrB] = b0.z; sBf[(lkB + 3) * 68 + lrB] = b0.w;
                sBf[(lkB + 4) * 68 + lrB] = b1.x; sBf[(lkB + 5) * 68 + lrB] = b1.y;
                sBf[(lkB + 6) * 68 + lrB] = b1.z; sBf[(lkB + 7) * 68 + lrB] = b1.w;
                __syncthreads();
#pragma unroll
                for (int kk = 0; kk < 32; kk++) {
                    double a0 = (double)sAf[kk * 36 + ty * 2 + 0];
                    double a1 = (double)sAf[kk * 36 + ty * 2 + 1];
                    float4 bq = *(const float4*)(sBf + kk * 68 + tx * 4);
                    double b0d = (double)bq.x, b1d = (double)bq.y;
                    double b2d = (double)bq.z, b3d = (double)bq.w;
                    acc[0][0] += a0 * b0d; acc[0][1] += a0 * b1d;
                    acc[0][2] += a0 * b2d; acc[0][3] += a0 * b3d;
                    acc[1][0] += a1 * b0d; acc[1][1] += a1 * b1d;
                    acc[1][2] += a1 * b2d; acc[1][3] += a1 * b3d;
                }
            }
#pragma unroll
            for (int i2 = 0; i2 < 2; i2++) {
                int rg = rowT * 32 + ty * 2 + i2;
                if (rg >= cnt) continue;
                int r = sRef[ty * 2 + i2];
                double ir = invn[b * NQ + r];
#pragma unroll
                for (int j2 = 0; j2 < 4; j2++) {
                    int c = colT * 64 + tx * 4 + j2;
                    double ic = invn[b * NQ + c];
                    sim[((long long)b * NQ + r) * NQ + c] = (float)(acc[i2][j2] * ir * ic);
                }
            }
        }
    } else {
        // ---------------- bf16 MFMA Gram GEMM: upper-tri 128x128 tiles ------
        const int gid = (id / 3) * 2 + (id % 3);   // 0..4095; only <2112 active
        if (gid >= 2112) return;                   // uniform per block
        const int b = gid / 528;
        int rem = gid % 528;
        int rT = 0;
        while (rem >= 32 - rT) { rem -= 32 - rT; rT++; }
        const int cT = rT + rem;
        const int rowBase = rT * 128;
        const int colBase = cT * 128;
        const __bf16* base = fnb + (long long)b * NQ * CQ;
        __bf16* smA = (__bf16*)smem;               // 128*32*2 = 8192 B (linear dest)
        __bf16* smB = (__bf16*)(smem + 8192);      // 8192 B

        const int lane = threadIdx.x & 63;
        const int w = threadIdx.x >> 6;
        const int wr = w >> 1, wc = w & 1;
        const int ldrow = lane >> 2;
        // stage-side swizzled source col (elems): ((lane&3)*8) ^ swz(row), row%16 = lane>>2
        const int ldcolS = ((lane & 3) * 8) ^ (((lane >> 3) & 3) << 3);
        // read-side swizzled col (elems): ((lane>>4)*8) ^ swz(row), row%16 = lane&15
        const int co = ((lane >> 4) * 8) ^ (((lane >> 1) & 3) << 3);

        floatx4 acc[4][4] = {};

        for (int k0 = 0; k0 < CQ; k0 += 32) {
            __syncthreads();
#pragma unroll
            for (int i = 0; i < 2; i++) {
                int rsub = w * 16 + i * 64;
                const __bf16* gA = base + (long long)(rowBase + rsub + ldrow) * CQ + k0 + ldcolS;
                const __bf16* gB = base + (long long)(colBase + rsub + ldrow) * CQ + k0 + ldcolS;
                __builtin_amdgcn_global_load_lds(
                    (const __attribute__((address_space(1))) void*)gA,
                    (__attribute__((address_space(3))) void*)(smA + rsub * 32), 16, 0, 0);
                __builtin_amdgcn_global_load_lds(
                    (const __attribute__((address_space(1))) void*)gB,
                    (__attribute__((address_space(3))) void*)(smB + rsub * 32), 16, 0, 0);
            }
            __syncthreads();

            bf16x8 af[4], bfv[4];
#pragma unroll
            for (int i = 0; i < 4; i++) {
                af[i]  = *(const bf16x8*)(smA + (wr * 64 + i * 16 + (lane & 15)) * 32 + co);
                bfv[i] = *(const bf16x8*)(smB + (wc * 64 + i * 16 + (lane & 15)) * 32 + co);
            }
#pragma unroll
            for (int i = 0; i < 4; i++)
#pragma unroll
                for (int j = 0; j < 4; j++)
                    acc[i][j] = __builtin_amdgcn_mfma_f32_16x16x32_bf16(af[i], bfv[j], acc[i][j], 0, 0, 0);
        }

        // Epilogue A: own tile (rT,cT). sim skips ref rows (f64 blocks own those);
        // match background zeros for all rows.
        float* simb = sim + (long long)b * NQ * NQ;
        float* matb = match + (long long)b * NQ * NQ;
        const uint8_t* mrow = maskc + b * NQ;
#pragma unroll
        for (int i = 0; i < 4; i++) {
            int r0 = rowBase + wr * 64 + i * 16 + (lane >> 4) * 4;
#pragma unroll
            for (int r = 0; r < 4; r++) {
                bool isRef = mrow[r0 + r] != 0;
#pragma unroll
                for (int j = 0; j < 4; j++) {
                    int c = colBase + wc * 64 + j * 16 + (lane & 15);
                    if (!isRef) simb[(long long)(r0 + r) * NQ + c] = acc[i][j][r];
                    matb[(long long)(r0 + r) * NQ + c] = 0.0f;
                }
            }
        }

        // Epilogue B: mirror tile (cT,rT) for off-diagonal blocks. Mirror row
        // index is c; skip sim write where c is a ref row (f64 owns it).
        // float4 at (c*NQ + r0) — r0 % 4 == 0, 16B aligned.
        if (rT != cT) {
            floatx4 zero4 = {0.0f, 0.0f, 0.0f, 0.0f};
#pragma unroll
            for (int i = 0; i < 4; i++) {
                int r0 = rowBase + wr * 64 + i * 16 + (lane >> 4) * 4;
#pragma unroll
                for (int j = 0; j < 4; j++) {
                    int c = colBase + wc * 64 + j * 16 + (lane & 15);
                    long long off = (long long)c * NQ + r0;
                    if (!mrow[c]) *(floatx4*)(simb + off) = acc[i][j];
                    *(floatx4*)(matb + off) = zero4;
                }
            }
        }
    }
}

// K3: per ref slot, max over non-ref cols (slot-based, no wasted blocks)
__global__ __launch_bounds__(256) void k_rowmax(const float* sim, const uint8_t* maskc,
                                                const int* refCount, const int* refIdx,
                                                float* maxv) {
    int b = blockIdx.y;
    int cnt = refCount[b];
    __shared__ float red[256];
    for (int slot = blockIdx.x; slot < cnt; slot += gridDim.x) {
        int row = refIdx[b * NQ + slot];
        const float* rp = sim + ((long long)b * NQ + row) * NQ;
        float mx = -INFINITY;
        for (int j = threadIdx.x; j < NQ; j += 256) {
            if (!maskc[b * NQ + j]) mx = fmaxf(mx, rp[j]);
        }
        __syncthreads();
        red[threadIdx.x] = mx;
        __syncthreads();
        for (int o = 128; o > 0; o >>= 1) {
            if (threadIdx.x < o) red[threadIdx.x] = fmaxf(red[threadIdx.x], red[threadIdx.x + o]);
            __syncthreads();
        }
        if (threadIdx.x == 0) maxv[b * NQ + slot] = red[0];
    }
}

// K4: lower median over slots [0,cnt) per batch (O(k^2) rank counting)
__global__ __launch_bounds__(256) void k_median(const float* maxv, const int* refCount,
                                                float* threshv, float* outth) {
    int b = blockIdx.x;
    int k = refCount[b];
    __shared__ float vals[NQ];
    __shared__ float result;
    for (int i = threadIdx.x; i < k; i += blockDim.x) vals[i] = maxv[b * NQ + i];
    __syncthreads();
    int med = (k - 1) / 2;
    for (int t0 = threadIdx.x; t0 < k; t0 += blockDim.x) {
        float v = vals[t0];
        int cl = 0, ce = 0;
        for (int j = 0; j < k; j++) {
            float w = vals[j];
            cl += (w < v) ? 1 : 0;
            ce += (w == v) ? 1 : 0;
        }
        if (cl <= med && med < cl + ce) result = v;  // unique value class; benign race
    }
    __syncthreads();
    if (threadIdx.x == 0) {
        threshv[b] = result;
        outth[b] = result;
    }
}

// K5: match bits for ref rows (background zeros already written by k_mega)
__global__ __launch_bounds__(256) void k_match(const float* sim, const uint8_t* maskc,
                                               const int* refCount, const int* refIdx,
                                               const float* threshv, float* match) {
    int b = blockIdx.y;
    int cnt = refCount[b];
    float th = threshv[b];
    const uint8_t* mb = maskc + b * NQ;
    for (int slot = blockIdx.x; slot < cnt; slot += gridDim.x) {
        int row = refIdx[b * NQ + slot];
        const float* rp = sim + ((long long)b * NQ + row) * NQ;
        float* op = match + ((long long)b * NQ + row) * NQ;
        for (int j = threadIdx.x * 4; j < NQ; j += 256 * 4) {
            float4 s = *(const float4*)(rp + j);
            float4 o;
            o.x = (!mb[j + 0] && s.x > th) ? 1.0f : 0.0f;
            o.y = (!mb[j + 1] && s.y > th) ? 1.0f : 0.0f;
            o.z = (!mb[j + 2] && s.z > th) ? 1.0f : 0.0f;
            o.w = (!mb[j + 3] && s.w > th) ? 1.0f : 0.0f;
            *(float4*)(op + j) = o;
        }
    }
}

extern "C" void kernel_launch(void* const* d_in, const int* in_sizes, int n_in,
                              void* d_out, int out_size, void* d_ws, size_t ws_size,
                              hipStream_t stream) {
    if (in_sizes[0] != BQ * NQ * CQ) return;
    if (ws_size < WS_NEED) return;  // d_ws observed ~2 GiB (poison fills)

    const float* x = (const float*)d_in[0];
    const void* mraw = d_in[1];
    float* out = (float*)d_out;
    uint8_t* ws = (uint8_t*)d_ws;

    int* ctr       = (int*)(ws + WS_CTR);
    int* refCount  = (int*)(ws + 16);
    float* threshv = (float*)(ws + WS_THRESH);
    uint8_t* maskc = ws + WS_MASK;
    int* refIdx    = (int*)(ws + WS_REFIDX);
    float* maxv    = (float*)(ws + WS_MAXV);
    double* invn   = (double*)(ws + WS_INVN);
    __bf16* fnb    = (__bf16*)(ws + WS_FNB);

    float* match = out;                                // [B,N,N] as 0/1 floats
    float* sim   = out + (long long)BQ * NQ * NQ;      // [B,N,N]
    float* outth = out + 2LL * BQ * NQ * NQ;           // [B]

    hipMemsetAsync(ws, 0, 4096, stream);  // counters

    k_detect<<<1, 256, 0, stream>>>((const uint8_t*)mraw, ctr);
    k_canon<<<(BQ * NQ + 255) / 256, 256, 0, stream>>>(mraw, ctr, maskc);
    k_compact<<<BQ, 256, 0, stream>>>(maskc, refCount, refIdx);
    k_prep<<<BQ * NQ, 128, 0, stream>>>(x, invn, fnb);
    k_mega<<<GRID_MEGA, 256, 0, stream>>>(fnb, x, invn, refCount, refIdx, maskc, sim, match);
    k_rowmax<<<dim3(256, BQ), 256, 0, stream>>>(sim, maskc, refCount, refIdx, maxv);
    k_median<<<BQ, 256, 0, stream>>>(maxv, refCount, threshv, outth);
    k_match<<<dim3(256, BQ), 256, 0, stream>>>(sim, maskc, refCount, refIdx, threshv, match);
}

// Round 4
// 959.861 us; speedup vs baseline: 1.0982x; 1.0377x over previous
//
#include <hip/hip_runtime.h>
#include <hip/hip_bf16.h>
#include <stdint.h>
#include <math.h>

// Problem constants (fixed-shape problem)
#define BQ 4
#define NQ 4096
#define CQ 1024

// ws layout (bytes)
#define WS_CTR      0         // int c123 @0, c3f @4; int refCount[4] @16
#define WS_THRESH   64        // float[4]
#define WS_MASK     256       // uint8[BQ*NQ] = 16384  -> ends 16640
#define WS_REFIDX   17408     // int[BQ*NQ]  = 65536  -> ends 82944
#define WS_MAXV     82944     // float[BQ*NQ]= 65536  -> ends 148480
#define WS_INVN     148480    // double[BQ*NQ]=131072 -> ends 279552 (8-aligned)
#define WS_FNB      (4u << 20)             // bf16[BQ*NQ*CQ] = 32 MB
#define WS_NEED     (WS_FNB + (32u << 20) + (1u << 20))

typedef __bf16 bf16x8 __attribute__((ext_vector_type(8)));
typedef float floatx4 __attribute__((ext_vector_type(4)));

// ---------------------------------------------------------------------------
// K0a: detect mask dtype. Reads only first BQ*NQ bytes (safe under u8/i32/f32).
__global__ void k_detect(const uint8_t* mraw, int* ctr) {
    int c123 = 0, c3f = 0;
    for (int i = threadIdx.x; i < BQ * NQ; i += blockDim.x) {
        uint8_t v = mraw[i];
        int m4 = i & 3;
        if (m4 != 0 && v != 0) c123++;
        if (m4 == 3 && v == 0x3F) c3f++;
    }
    atomicAdd(&ctr[0], c123);
    atomicAdd(&ctr[1], c3f);
}

// K0b: canonicalize mask to uint8 0/1
__global__ void k_canon(const void* mraw, const int* ctr, uint8_t* maskc) {
    int i = blockIdx.x * blockDim.x + threadIdx.x;
    if (i >= BQ * NQ) return;
    int c123 = ctr[0], c3f = ctr[1];
    uint8_t v;
    if (c3f > 64) {
        v = (((const float*)mraw)[i] != 0.0f) ? 1 : 0;
    } else if (c123 == 0) {
        v = (((const int*)mraw)[i] != 0) ? 1 : 0;
    } else {
        v = (((const uint8_t*)mraw)[i] != 0) ? 1 : 0;
    }
    maskc[i] = v;
}

// K0c: compact ref-row indices per batch
__global__ void k_compact(const uint8_t* maskc, int* refCount, int* refIdx) {
    int b = blockIdx.x;
    for (int i = threadIdx.x; i < NQ; i += blockDim.x) {
        if (maskc[b * NQ + i]) {
            int p = atomicAdd(&refCount[b], 1);
            refIdx[b * NQ + p] = i;
        }
    }
}

// K1: fused row norm (f64) + bf16 normalized convert. One 128-thread block/row.
__global__ __launch_bounds__(128) void k_prep(const float* x, double* invn, __bf16* fnb) {
    int row = blockIdx.x;  // 0..BQ*NQ-1
    int t = threadIdx.x;
    const float4* xr = (const float4*)(x + (long long)row * CQ);
    float4 a = xr[t * 2 + 0];
    float4 c = xr[t * 2 + 1];
    double s = (double)a.x * a.x + (double)a.y * a.y + (double)a.z * a.z + (double)a.w * a.w
             + (double)c.x * c.x + (double)c.y * c.y + (double)c.z * c.z + (double)c.w * c.w;
    __shared__ double red[128];
    __shared__ double invs;
    red[t] = s;
    __syncthreads();
    for (int o = 64; o > 0; o >>= 1) {
        if (t < o) red[t] += red[t + o];
        __syncthreads();
    }
    if (t == 0) {
        double inv = 1.0 / fmax(sqrt(red[0]), 1e-12);
        invn[row] = inv;
        invs = inv;
    }
    __syncthreads();
    float ir = (float)invs;
    bf16x8 o8;
    o8[0] = (__bf16)(a.x * ir); o8[1] = (__bf16)(a.y * ir);
    o8[2] = (__bf16)(a.z * ir); o8[3] = (__bf16)(a.w * ir);
    o8[4] = (__bf16)(c.x * ir); o8[5] = (__bf16)(c.y * ir);
    o8[6] = (__bf16)(c.z * ir); o8[7] = (__bf16)(c.w * ir);
    *(bf16x8*)(fnb + (long long)row * CQ + t * 8) = o8;
}

// K2: fused mega-kernel.
//   id%3==2 -> f64 VECTOR ref-row GEMM (R1-proven numerics; new 32x128 tile,
//              4x4 per-thread blocking, k-major LDS, b128 fragment reads)
//   else    -> bf16 MFMA Gram GEMM (upper-tri 128x128 tiles, R1-proven)
//
// R3: the f64-MFMA experiment (R2) is abandoned — the f64 lane mapping on
// gfx950 is unverified and produced wrong results. Instead the R1 vector-f64
// path gets better issue efficiency: per 16 f64 FMA we now pay 8 cvt + 2
// ds_read_b128 (was per 8 FMA: 6 cvt + 3 LDS ops). f64 accumulation order per
// output is ascending-k exactly as R1 -> bit-identical sums.
#define GRID_MEGA 3168  // 2112 bf16 (id%3!=2) + 1056 f64 slots (1024 active)
__global__ __launch_bounds__(256) void k_mega(const __bf16* fnb, const float* x,
                                              const double* invn, const int* refCount,
                                              const int* refIdx, const uint8_t* maskc,
                                              float* sim, float* match) {
    __shared__ __align__(16) char smem[24576];
    const int t = threadIdx.x;
    const int id = blockIdx.x;

    if ((id % 3) == 2) {
        // ---------------- f64 vector ref-row GEMM: 32 ref rows x 128 cols ---
        const int fid = id / 3;            // 0..1055
        if (fid >= 1024) return;
        const int b = fid >> 8;            // fid = b*256 + rowT0*32 + colT
        const int rowT0 = (fid >> 5) & 7;
        const int colT = fid & 31;
        const int cnt = refCount[b];
        float* sA = (float*)smem;                  // k-major [32k][36] = 4608 B
        float* sB = (float*)(smem + 4608);         // k-major [32k][132] = 16896 B
        int* sRef = (int*)(smem + 21504);          // [32] -> ends 21632
        const float* xb = x + (long long)b * NQ * CQ;
        const int arow = t >> 3, ak0 = (t & 7) * 4;    // A staging: row, k base
        const int bcol = t >> 1, bk0 = (t & 1) * 16;   // B staging: col, k base
        const int ty = t >> 5, tx = t & 31;            // compute: 4 rows x 4 cols

        for (int rowT = rowT0; rowT * 32 < cnt; rowT += 8) {  // grid-stride
            __syncthreads();
            if (t < 32) {
                int rg = rowT * 32 + t;
                sRef[t] = (rg < cnt) ? refIdx[b * NQ + rg] : refIdx[b * NQ];
            }
            __syncthreads();
            const int garow = sRef[arow];
            const int gbrow = colT * 128 + bcol;
            double acc[4][4] = {};
            for (int k0 = 0; k0 < CQ; k0 += 32) {
                float4 av  = *(const float4*)(xb + (long long)garow * CQ + k0 + ak0);
                float4 bv0 = *(const float4*)(xb + (long long)gbrow * CQ + k0 + bk0);
                float4 bv1 = *(const float4*)(xb + (long long)gbrow * CQ + k0 + bk0 + 4);
                float4 bv2 = *(const float4*)(xb + (long long)gbrow * CQ + k0 + bk0 + 8);
                float4 bv3 = *(const float4*)(xb + (long long)gbrow * CQ + k0 + bk0 + 12);
                __syncthreads();
                sA[(ak0 + 0) * 36 + arow] = av.x;
                sA[(ak0 + 1) * 36 + arow] = av.y;
                sA[(ak0 + 2) * 36 + arow] = av.z;
                sA[(ak0 + 3) * 36 + arow] = av.w;
                sB[(bk0 +  0) * 132 + bcol] = bv0.x;
                sB[(bk0 +  1) * 132 + bcol] = bv0.y;
                sB[(bk0 +  2) * 132 + bcol] = bv0.z;
                sB[(bk0 +  3) * 132 + bcol] = bv0.w;
                sB[(bk0 +  4) * 132 + bcol] = bv1.x;
                sB[(bk0 +  5) * 132 + bcol] = bv1.y;
                sB[(bk0 +  6) * 132 + bcol] = bv1.z;
                sB[(bk0 +  7) * 132 + bcol] = bv1.w;
                sB[(bk0 +  8) * 132 + bcol] = bv2.x;
                sB[(bk0 +  9) * 132 + bcol] = bv2.y;
                sB[(bk0 + 10) * 132 + bcol] = bv2.z;
                sB[(bk0 + 11) * 132 + bcol] = bv2.w;
                sB[(bk0 + 12) * 132 + bcol] = bv3.x;
                sB[(bk0 + 13) * 132 + bcol] = bv3.y;
                sB[(bk0 + 14) * 132 + bcol] = bv3.z;
                sB[(bk0 + 15) * 132 + bcol] = bv3.w;
                __syncthreads();
#pragma unroll 4
                for (int m = 0; m < 32; m++) {
                    float4 a4 = *(const float4*)(sA + m * 36 + ty * 4);
                    float4 b4 = *(const float4*)(sB + m * 132 + tx * 4);
                    double a0 = (double)a4.x, a1 = (double)a4.y;
                    double a2 = (double)a4.z, a3 = (double)a4.w;
                    double b0 = (double)b4.x, b1 = (double)b4.y;
                    double b2 = (double)b4.z, b3 = (double)b4.w;
                    acc[0][0] += a0 * b0; acc[0][1] += a0 * b1;
                    acc[0][2] += a0 * b2; acc[0][3] += a0 * b3;
                    acc[1][0] += a1 * b0; acc[1][1] += a1 * b1;
                    acc[1][2] += a1 * b2; acc[1][3] += a1 * b3;
                    acc[2][0] += a2 * b0; acc[2][1] += a2 * b1;
                    acc[2][2] += a2 * b2; acc[2][3] += a2 * b3;
                    acc[3][0] += a3 * b0; acc[3][1] += a3 * b1;
                    acc[3][2] += a3 * b2; acc[3][3] += a3 * b3;
                }
            }
            // Epilogue: rows ty*4+i (local), cols colT*128 + tx*4+j.
            const int cbase = colT * 128 + tx * 4;
            const double ic0 = invn[b * NQ + cbase + 0];
            const double ic1 = invn[b * NQ + cbase + 1];
            const double ic2 = invn[b * NQ + cbase + 2];
            const double ic3 = invn[b * NQ + cbase + 3];
#pragma unroll
            for (int i = 0; i < 4; i++) {
                int rl = ty * 4 + i;
                if (rowT * 32 + rl >= cnt) continue;
                int r = sRef[rl];
                double ir = invn[b * NQ + r];
                float4 o;
                o.x = (float)(acc[i][0] * ir * ic0);
                o.y = (float)(acc[i][1] * ir * ic1);
                o.z = (float)(acc[i][2] * ir * ic2);
                o.w = (float)(acc[i][3] * ir * ic3);
                *(float4*)(sim + ((long long)b * NQ + r) * NQ + cbase) = o;
            }
        }
    } else {
        // ---------------- bf16 MFMA Gram GEMM: upper-tri 128x128 tiles ------
        const int gid = (id / 3) * 2 + (id % 3);   // 0..2111 exact
        const int b = gid / 528;
        int rem = gid % 528;
        int rT = 0;
        while (rem >= 32 - rT) { rem -= 32 - rT; rT++; }
        const int cT = rT + rem;
        const int rowBase = rT * 128;
        const int colBase = cT * 128;
        const __bf16* base = fnb + (long long)b * NQ * CQ;
        __bf16* smA = (__bf16*)smem;               // 128*32*2 = 8192 B (linear dest)
        __bf16* smB = (__bf16*)(smem + 8192);      // 8192 B

        const int lane = threadIdx.x & 63;
        const int w = threadIdx.x >> 6;
        const int wr = w >> 1, wc = w & 1;
        const int ldrow = lane >> 2;
        // stage-side swizzled source col (elems): ((lane&3)*8) ^ swz(row), row%16 = lane>>2
        const int ldcolS = ((lane & 3) * 8) ^ (((lane >> 3) & 3) << 3);
        // read-side swizzled col (elems): ((lane>>4)*8) ^ swz(row), row%16 = lane&15
        const int co = ((lane >> 4) * 8) ^ (((lane >> 1) & 3) << 3);

        floatx4 acc[4][4] = {};

        for (int k0 = 0; k0 < CQ; k0 += 32) {
            __syncthreads();
#pragma unroll
            for (int i = 0; i < 2; i++) {
                int rsub = w * 16 + i * 64;
                const __bf16* gA = base + (long long)(rowBase + rsub + ldrow) * CQ + k0 + ldcolS;
                const __bf16* gB = base + (long long)(colBase + rsub + ldrow) * CQ + k0 + ldcolS;
                __builtin_amdgcn_global_load_lds(
                    (const __attribute__((address_space(1))) void*)gA,
                    (__attribute__((address_space(3))) void*)(smA + rsub * 32), 16, 0, 0);
                __builtin_amdgcn_global_load_lds(
                    (const __attribute__((address_space(1))) void*)gB,
                    (__attribute__((address_space(3))) void*)(smB + rsub * 32), 16, 0, 0);
            }
            __syncthreads();

            bf16x8 af[4], bfv[4];
#pragma unroll
            for (int i = 0; i < 4; i++) {
                af[i]  = *(const bf16x8*)(smA + (wr * 64 + i * 16 + (lane & 15)) * 32 + co);
                bfv[i] = *(const bf16x8*)(smB + (wc * 64 + i * 16 + (lane & 15)) * 32 + co);
            }
#pragma unroll
            for (int i = 0; i < 4; i++)
#pragma unroll
                for (int j = 0; j < 4; j++)
                    acc[i][j] = __builtin_amdgcn_mfma_f32_16x16x32_bf16(af[i], bfv[j], acc[i][j], 0, 0, 0);
        }

        // Epilogue A: own tile (rT,cT). sim skips ref rows (f64 blocks own those);
        // match background zeros for all rows.
        float* simb = sim + (long long)b * NQ * NQ;
        float* matb = match + (long long)b * NQ * NQ;
        const uint8_t* mrow = maskc + b * NQ;
#pragma unroll
        for (int i = 0; i < 4; i++) {
            int r0 = rowBase + wr * 64 + i * 16 + (lane >> 4) * 4;
#pragma unroll
            for (int r = 0; r < 4; r++) {
                bool isRef = mrow[r0 + r] != 0;
#pragma unroll
                for (int j = 0; j < 4; j++) {
                    int c = colBase + wc * 64 + j * 16 + (lane & 15);
                    if (!isRef) simb[(long long)(r0 + r) * NQ + c] = acc[i][j][r];
                    matb[(long long)(r0 + r) * NQ + c] = 0.0f;
                }
            }
        }

        // Epilogue B: mirror tile (cT,rT) for off-diagonal blocks. Mirror row
        // index is c; skip sim write where c is a ref row (f64 owns it).
        // float4 at (c*NQ + r0) — r0 % 4 == 0, 16B aligned.
        if (rT != cT) {
            floatx4 zero4 = {0.0f, 0.0f, 0.0f, 0.0f};
#pragma unroll
            for (int i = 0; i < 4; i++) {
                int r0 = rowBase + wr * 64 + i * 16 + (lane >> 4) * 4;
#pragma unroll
                for (int j = 0; j < 4; j++) {
                    int c = colBase + wc * 64 + j * 16 + (lane & 15);
                    long long off = (long long)c * NQ + r0;
                    if (!mrow[c]) *(floatx4*)(simb + off) = acc[i][j];
                    *(floatx4*)(matb + off) = zero4;
                }
            }
        }
    }
}

// K3: per ref slot, max over non-ref cols (slot-based, no wasted blocks)
__global__ __launch_bounds__(256) void k_rowmax(const float* sim, const uint8_t* maskc,
                                                const int* refCount, const int* refIdx,
                                                float* maxv) {
    int b = blockIdx.y;
    int cnt = refCount[b];
    __shared__ float red[256];
    for (int slot = blockIdx.x; slot < cnt; slot += gridDim.x) {
        int row = refIdx[b * NQ + slot];
        const float* rp = sim + ((long long)b * NQ + row) * NQ;
        float mx = -INFINITY;
        for (int j = threadIdx.x; j < NQ; j += 256) {
            if (!maskc[b * NQ + j]) mx = fmaxf(mx, rp[j]);
        }
        __syncthreads();
        red[threadIdx.x] = mx;
        __syncthreads();
        for (int o = 128; o > 0; o >>= 1) {
            if (threadIdx.x < o) red[threadIdx.x] = fmaxf(red[threadIdx.x], red[threadIdx.x + o]);
            __syncthreads();
        }
        if (threadIdx.x == 0) maxv[b * NQ + slot] = red[0];
    }
}

// K4: lower median over slots [0,cnt) per batch (O(k^2) rank counting)
__global__ __launch_bounds__(256) void k_median(const float* maxv, const int* refCount,
                                                float* threshv, float* outth) {
    int b = blockIdx.x;
    int k = refCount[b];
    __shared__ float vals[NQ];
    __shared__ float result;
    for (int i = threadIdx.x; i < k; i += blockDim.x) vals[i] = maxv[b * NQ + i];
    __syncthreads();
    int med = (k - 1) / 2;
    for (int t0 = threadIdx.x; t0 < k; t0 += blockDim.x) {
        float v = vals[t0];
        int cl = 0, ce = 0;
        for (int j = 0; j < k; j++) {
            float w = vals[j];
            cl += (w < v) ? 1 : 0;
            ce += (w == v) ? 1 : 0;
        }
        if (cl <= med && med < cl + ce) result = v;  // unique value class; benign race
    }
    __syncthreads();
    if (threadIdx.x == 0) {
        threshv[b] = result;
        outth[b] = result;
    }
}

// K5: match bits for ref rows (background zeros already written by k_mega)
__global__ __launch_bounds__(256) void k_match(const float* sim, const uint8_t* maskc,
                                               const int* refCount, const int* refIdx,
                                               const float* threshv, float* match) {
    int b = blockIdx.y;
    int cnt = refCount[b];
    float th = threshv[b];
    const uint8_t* mb = maskc + b * NQ;
    for (int slot = blockIdx.x; slot < cnt; slot += gridDim.x) {
        int row = refIdx[b * NQ + slot];
        const float* rp = sim + ((long long)b * NQ + row) * NQ;
        float* op = match + ((long long)b * NQ + row) * NQ;
        for (int j = threadIdx.x * 4; j < NQ; j += 256 * 4) {
            float4 s = *(const float4*)(rp + j);
            float4 o;
            o.x = (!mb[j + 0] && s.x > th) ? 1.0f : 0.0f;
            o.y = (!mb[j + 1] && s.y > th) ? 1.0f : 0.0f;
            o.z = (!mb[j + 2] && s.z > th) ? 1.0f : 0.0f;
            o.w = (!mb[j + 3] && s.w > th) ? 1.0f : 0.0f;
            *(float4*)(op + j) = o;
        }
    }
}

extern "C" void kernel_launch(void* const* d_in, const int* in_sizes, int n_in,
                              void* d_out, int out_size, void* d_ws, size_t ws_size,
                              hipStream_t stream) {
    if (in_sizes[0] != BQ * NQ * CQ) return;
    if (ws_size < WS_NEED) return;  // d_ws observed ~2 GiB (poison fills)

    const float* x = (const float*)d_in[0];
    const void* mraw = d_in[1];
    float* out = (float*)d_out;
    uint8_t* ws = (uint8_t*)d_ws;

    int* ctr       = (int*)(ws + WS_CTR);
    int* refCount  = (int*)(ws + 16);
    float* threshv = (float*)(ws + WS_THRESH);
    uint8_t* maskc = ws + WS_MASK;
    int* refIdx    = (int*)(ws + WS_REFIDX);
    float* maxv    = (float*)(ws + WS_MAXV);
    double* invn   = (double*)(ws + WS_INVN);
    __bf16* fnb    = (__bf16*)(ws + WS_FNB);

    float* match = out;                                // [B,N,N] as 0/1 floats
    float* sim   = out + (long long)BQ * NQ * NQ;      // [B,N,N]
    float* outth = out + 2LL * BQ * NQ * NQ;           // [B]

    hipMemsetAsync(ws, 0, 4096, stream);  // counters

    k_detect<<<1, 256, 0, stream>>>((const uint8_t*)mraw, ctr);
    k_canon<<<(BQ * NQ + 255) / 256, 256, 0, stream>>>(mraw, ctr, maskc);
    k_compact<<<BQ, 256, 0, stream>>>(maskc, refCount, refIdx);
    k_prep<<<BQ * NQ, 128, 0, stream>>>(x, invn, fnb);
    k_mega<<<GRID_MEGA, 256, 0, stream>>>(fnb, x, invn, refCount, refIdx, maskc, sim, match);
    k_rowmax<<<dim3(256, BQ), 256, 0, stream>>>(sim, maskc, refCount, refIdx, maxv);
    k_median<<<BQ, 256, 0, stream>>>(maxv, refCount, threshv, outth);
    k_match<<<dim3(256, BQ), 256, 0, stream>>>(sim, maskc, refCount, refIdx, threshv, match);
}

// Round 5
// 845.881 us; speedup vs baseline: 1.2462x; 1.1347x over previous
//
#include <hip/hip_runtime.h>
#include <hip/hip_bf16.h>
#include <stdint.h>
#include <math.h>

// Problem constants (fixed-shape problem)
#define BQ 4
#define NQ 4096
#define CQ 1024

// ws layout (bytes)
#define WS_CTR      0         // int c123 @0, c3f @4; int refCount[4] @16
#define WS_THRESH   64        // float[4]
#define WS_MASK     256       // uint8[BQ*NQ] = 16384  -> ends 16640
#define WS_REFIDX   17408     // int[BQ*NQ]  = 65536  -> ends 82944
#define WS_MAXV     82944     // float[BQ*NQ]= 65536  -> ends 148480
#define WS_FNH      (4u << 20)               // bf16 hi[BQ*NQ*CQ] = 32 MB
#define WS_FNL      (WS_FNH + (32u << 20))   // bf16 lo[BQ*NQ*CQ] = 32 MB
#define WS_NEED     (WS_FNL + (32u << 20) + (1u << 20))

typedef __bf16 bf16x8 __attribute__((ext_vector_type(8)));
typedef float floatx4 __attribute__((ext_vector_type(4)));

// ---------------------------------------------------------------------------
// K0a: detect mask dtype. Reads only first BQ*NQ bytes (safe under u8/i32/f32).
__global__ void k_detect(const uint8_t* mraw, int* ctr) {
    int c123 = 0, c3f = 0;
    for (int i = threadIdx.x; i < BQ * NQ; i += blockDim.x) {
        uint8_t v = mraw[i];
        int m4 = i & 3;
        if (m4 != 0 && v != 0) c123++;
        if (m4 == 3 && v == 0x3F) c3f++;
    }
    atomicAdd(&ctr[0], c123);
    atomicAdd(&ctr[1], c3f);
}

// K0b: canonicalize mask to uint8 0/1
__global__ void k_canon(const void* mraw, const int* ctr, uint8_t* maskc) {
    int i = blockIdx.x * blockDim.x + threadIdx.x;
    if (i >= BQ * NQ) return;
    int c123 = ctr[0], c3f = ctr[1];
    uint8_t v;
    if (c3f > 64) {
        v = (((const float*)mraw)[i] != 0.0f) ? 1 : 0;
    } else if (c123 == 0) {
        v = (((const int*)mraw)[i] != 0) ? 1 : 0;
    } else {
        v = (((const uint8_t*)mraw)[i] != 0) ? 1 : 0;
    }
    maskc[i] = v;
}

// K0c: compact ref-row indices per batch
__global__ void k_compact(const uint8_t* maskc, int* refCount, int* refIdx) {
    int b = blockIdx.x;
    for (int i = threadIdx.x; i < NQ; i += blockDim.x) {
        if (maskc[b * NQ + i]) {
            int p = atomicAdd(&refCount[b], 1);
            refIdx[b * NQ + p] = i;
        }
    }
}

// K1: fused row norm (f64) + bf16 SPLIT convert: xn = h + l with h = bf16(xn),
// l = bf16(xn - h). h+l represents the f32 normalized value to ~2^-18 rel,
// enabling near-f32-exact Gram via 4 MFMA passes (hh+hl+lh+ll).
// bf16 (not fp16) keeps l in normal range (bf16 min normal 1.2e-38).
__global__ __launch_bounds__(128) void k_prep(const float* x, __bf16* fnh, __bf16* fnl) {
    int row = blockIdx.x;  // 0..BQ*NQ-1
    int t = threadIdx.x;
    const float4* xr = (const float4*)(x + (long long)row * CQ);
    float4 a = xr[t * 2 + 0];
    float4 c = xr[t * 2 + 1];
    double s = (double)a.x * a.x + (double)a.y * a.y + (double)a.z * a.z + (double)a.w * a.w
             + (double)c.x * c.x + (double)c.y * c.y + (double)c.z * c.z + (double)c.w * c.w;
    __shared__ double red[128];
    __shared__ double invs;
    red[t] = s;
    __syncthreads();
    for (int o = 64; o > 0; o >>= 1) {
        if (t < o) red[t] += red[t + o];
        __syncthreads();
    }
    if (t == 0) invs = 1.0 / fmax(sqrt(red[0]), 1e-12);
    __syncthreads();
    float ir = (float)invs;
    float v[8] = {a.x, a.y, a.z, a.w, c.x, c.y, c.z, c.w};
    bf16x8 h8, l8;
#pragma unroll
    for (int j = 0; j < 8; j++) {
        float xn = v[j] * ir;
        __bf16 h = (__bf16)xn;
        h8[j] = h;
        l8[j] = (__bf16)(xn - (float)h);
    }
    *(bf16x8*)(fnh + (long long)row * CQ + t * 8) = h8;
    *(bf16x8*)(fnl + (long long)row * CQ + t * 8) = l8;
}

// K2: uniform split-bf16 MFMA Gram GEMM, upper-tri 128x128 tiles.
//   sim = (h_r+l_r)·(h_c+l_c) via 4 chained MFMA passes (hh, hl, lh, ll) into
//   a single f32 accumulator — near-f32-exact (split err ~1e-7, chain ~5e-8),
//   so ref rows no longer need a separate f64 path (R4's 45%-VALUBusy pole).
//   No invn scaling needed (inputs pre-normalized); no isRef special-casing.
// XCD swizzle: 2112 blocks = 8 x 264 (bijective); consecutive gids share the
// same rT A-panel (512 KB h+l) -> per-XCD L2 reuse.
// LDS swizzle (T2/rule #21): unchanged from R1 (verified): linear LDS dest,
// pre-swizzled global source col, same XOR on the read.
#define GRID_MEGA 2112
__global__ __launch_bounds__(256) void k_mega(const __bf16* fnh, const __bf16* fnl,
                                              float* sim, float* match) {
    __shared__ __align__(16) char smem[32768];
    const int id = blockIdx.x;
    const int gid = (id & 7) * 264 + (id >> 3);   // XCD-contiguous tri order
    const int b = gid / 528;
    int rem = gid % 528;
    int rT = 0;
    while (rem >= 32 - rT) { rem -= 32 - rT; rT++; }
    const int cT = rT + rem;
    const int rowBase = rT * 128;
    const int colBase = cT * 128;
    const __bf16* baseh = fnh + (long long)b * NQ * CQ;
    const __bf16* basel = fnl + (long long)b * NQ * CQ;
    __bf16* smAh = (__bf16*)smem;               // 128*32*2 = 8192 B each
    __bf16* smAl = (__bf16*)(smem + 8192);
    __bf16* smBh = (__bf16*)(smem + 16384);
    __bf16* smBl = (__bf16*)(smem + 24576);

    const int lane = threadIdx.x & 63;
    const int w = threadIdx.x >> 6;
    const int wr = w >> 1, wc = w & 1;
    const int ldrow = lane >> 2;
    // stage-side swizzled source col (elems): ((lane&3)*8) ^ swz(row), row%16 = lane>>2
    const int ldcolS = ((lane & 3) * 8) ^ (((lane >> 3) & 3) << 3);
    // read-side swizzled col (elems): ((lane>>4)*8) ^ swz(row), row%16 = lane&15
    const int co = ((lane >> 4) * 8) ^ (((lane >> 1) & 3) << 3);

    floatx4 acc[4][4] = {};

    for (int k0 = 0; k0 < CQ; k0 += 32) {
        __syncthreads();
#pragma unroll
        for (int i = 0; i < 2; i++) {
            int rsub = w * 16 + i * 64;
            long long offA = (long long)(rowBase + rsub + ldrow) * CQ + k0 + ldcolS;
            long long offB = (long long)(colBase + rsub + ldrow) * CQ + k0 + ldcolS;
            __builtin_amdgcn_global_load_lds(
                (const __attribute__((address_space(1))) void*)(baseh + offA),
                (__attribute__((address_space(3))) void*)(smAh + rsub * 32), 16, 0, 0);
            __builtin_amdgcn_global_load_lds(
                (const __attribute__((address_space(1))) void*)(basel + offA),
                (__attribute__((address_space(3))) void*)(smAl + rsub * 32), 16, 0, 0);
            __builtin_amdgcn_global_load_lds(
                (const __attribute__((address_space(1))) void*)(baseh + offB),
                (__attribute__((address_space(3))) void*)(smBh + rsub * 32), 16, 0, 0);
            __builtin_amdgcn_global_load_lds(
                (const __attribute__((address_space(1))) void*)(basel + offB),
                (__attribute__((address_space(3))) void*)(smBl + rsub * 32), 16, 0, 0);
        }
        __syncthreads();

        bf16x8 ah[4], al[4];
#pragma unroll
        for (int i = 0; i < 4; i++) {
            int ra = (wr * 64 + i * 16 + (lane & 15)) * 32 + co;
            ah[i] = *(const bf16x8*)(smAh + ra);
            al[i] = *(const bf16x8*)(smAl + ra);
        }
#pragma unroll
        for (int j = 0; j < 4; j++) {
            int rb = (wc * 64 + j * 16 + (lane & 15)) * 32 + co;
            bf16x8 bh = *(const bf16x8*)(smBh + rb);
            bf16x8 bl = *(const bf16x8*)(smBl + rb);
#pragma unroll
            for (int i = 0; i < 4; i++) {
                acc[i][j] = __builtin_amdgcn_mfma_f32_16x16x32_bf16(ah[i], bh, acc[i][j], 0, 0, 0);
                acc[i][j] = __builtin_amdgcn_mfma_f32_16x16x32_bf16(ah[i], bl, acc[i][j], 0, 0, 0);
                acc[i][j] = __builtin_amdgcn_mfma_f32_16x16x32_bf16(al[i], bh, acc[i][j], 0, 0, 0);
                acc[i][j] = __builtin_amdgcn_mfma_f32_16x16x32_bf16(al[i], bl, acc[i][j], 0, 0, 0);
            }
        }
    }

    // Epilogue A: own tile (rT,cT): sim values + match zeros, all rows.
    float* simb = sim + (long long)b * NQ * NQ;
    float* matb = match + (long long)b * NQ * NQ;
#pragma unroll
    for (int i = 0; i < 4; i++) {
        int r0 = rowBase + wr * 64 + i * 16 + (lane >> 4) * 4;
#pragma unroll
        for (int r = 0; r < 4; r++) {
#pragma unroll
            for (int j = 0; j < 4; j++) {
                int c = colBase + wc * 64 + j * 16 + (lane & 15);
                simb[(long long)(r0 + r) * NQ + c] = acc[i][j][r];
                matb[(long long)(r0 + r) * NQ + c] = 0.0f;
            }
        }
    }
    // Epilogue B: mirror tile (cT,rT) for off-diagonal blocks (bit-identical
    // by operand symmetry). float4 at (c*NQ + r0), 16B aligned.
    if (rT != cT) {
        floatx4 zero4 = {0.0f, 0.0f, 0.0f, 0.0f};
#pragma unroll
        for (int i = 0; i < 4; i++) {
            int r0 = rowBase + wr * 64 + i * 16 + (lane >> 4) * 4;
#pragma unroll
            for (int j = 0; j < 4; j++) {
                int c = colBase + wc * 64 + j * 16 + (lane & 15);
                long long off = (long long)c * NQ + r0;
                *(floatx4*)(simb + off) = acc[i][j];
                *(floatx4*)(matb + off) = zero4;
            }
        }
    }
}

// K3: per ref slot, max over non-ref cols (slot-based, no wasted blocks)
__global__ __launch_bounds__(256) void k_rowmax(const float* sim, const uint8_t* maskc,
                                                const int* refCount, const int* refIdx,
                                                float* maxv) {
    int b = blockIdx.y;
    int cnt = refCount[b];
    __shared__ float red[256];
    for (int slot = blockIdx.x; slot < cnt; slot += gridDim.x) {
        int row = refIdx[b * NQ + slot];
        const float* rp = sim + ((long long)b * NQ + row) * NQ;
        float mx = -INFINITY;
        for (int j = threadIdx.x; j < NQ; j += 256) {
            if (!maskc[b * NQ + j]) mx = fmaxf(mx, rp[j]);
        }
        __syncthreads();
        red[threadIdx.x] = mx;
        __syncthreads();
        for (int o = 128; o > 0; o >>= 1) {
            if (threadIdx.x < o) red[threadIdx.x] = fmaxf(red[threadIdx.x], red[threadIdx.x + o]);
            __syncthreads();
        }
        if (threadIdx.x == 0) maxv[b * NQ + slot] = red[0];
    }
}

// K4: lower median over slots [0,cnt) per batch (O(k^2) rank counting)
__global__ __launch_bounds__(256) void k_median(const float* maxv, const int* refCount,
                                                float* threshv, float* outth) {
    int b = blockIdx.x;
    int k = refCount[b];
    __shared__ float vals[NQ];
    __shared__ float result;
    for (int i = threadIdx.x; i < k; i += blockDim.x) vals[i] = maxv[b * NQ + i];
    __syncthreads();
    int med = (k - 1) / 2;
    for (int t0 = threadIdx.x; t0 < k; t0 += blockDim.x) {
        float v = vals[t0];
        int cl = 0, ce = 0;
        for (int j = 0; j < k; j++) {
            float w = vals[j];
            cl += (w < v) ? 1 : 0;
            ce += (w == v) ? 1 : 0;
        }
        if (cl <= med && med < cl + ce) result = v;  // unique value class; benign race
    }
    __syncthreads();
    if (threadIdx.x == 0) {
        threshv[b] = result;
        outth[b] = result;
    }
}

// K5: match bits for ref rows (background zeros already written by k_mega)
__global__ __launch_bounds__(256) void k_match(const float* sim, const uint8_t* maskc,
                                               const int* refCount, const int* refIdx,
                                               const float* threshv, float* match) {
    int b = blockIdx.y;
    int cnt = refCount[b];
    float th = threshv[b];
    const uint8_t* mb = maskc + b * NQ;
    for (int slot = blockIdx.x; slot < cnt; slot += gridDim.x) {
        int row = refIdx[b * NQ + slot];
        const float* rp = sim + ((long long)b * NQ + row) * NQ;
        float* op = match + ((long long)b * NQ + row) * NQ;
        for (int j = threadIdx.x * 4; j < NQ; j += 256 * 4) {
            float4 s = *(const float4*)(rp + j);
            float4 o;
            o.x = (!mb[j + 0] && s.x > th) ? 1.0f : 0.0f;
            o.y = (!mb[j + 1] && s.y > th) ? 1.0f : 0.0f;
            o.z = (!mb[j + 2] && s.z > th) ? 1.0f : 0.0f;
            o.w = (!mb[j + 3] && s.w > th) ? 1.0f : 0.0f;
            *(float4*)(op + j) = o;
        }
    }
}

extern "C" void kernel_launch(void* const* d_in, const int* in_sizes, int n_in,
                              void* d_out, int out_size, void* d_ws, size_t ws_size,
                              hipStream_t stream) {
    if (in_sizes[0] != BQ * NQ * CQ) return;
    if (ws_size < WS_NEED) return;  // d_ws observed ~2 GiB (poison fills)

    const float* x = (const float*)d_in[0];
    const void* mraw = d_in[1];
    float* out = (float*)d_out;
    uint8_t* ws = (uint8_t*)d_ws;

    int* ctr       = (int*)(ws + WS_CTR);
    int* refCount  = (int*)(ws + 16);
    float* threshv = (float*)(ws + WS_THRESH);
    uint8_t* maskc = ws + WS_MASK;
    int* refIdx    = (int*)(ws + WS_REFIDX);
    float* maxv    = (float*)(ws + WS_MAXV);
    __bf16* fnh    = (__bf16*)(ws + WS_FNH);
    __bf16* fnl    = (__bf16*)(ws + WS_FNL);

    float* match = out;                                // [B,N,N] as 0/1 floats
    float* sim   = out + (long long)BQ * NQ * NQ;      // [B,N,N]
    float* outth = out + 2LL * BQ * NQ * NQ;           // [B]

    hipMemsetAsync(ws, 0, 4096, stream);  // counters

    k_detect<<<1, 256, 0, stream>>>((const uint8_t*)mraw, ctr);
    k_canon<<<(BQ * NQ + 255) / 256, 256, 0, stream>>>(mraw, ctr, maskc);
    k_compact<<<BQ, 256, 0, stream>>>(maskc, refCount, refIdx);
    k_prep<<<BQ * NQ, 128, 0, stream>>>(x, fnh, fnl);
    k_mega<<<GRID_MEGA, 256, 0, stream>>>(fnh, fnl, sim, match);
    k_rowmax<<<dim3(256, BQ), 256, 0, stream>>>(sim, maskc, refCount, refIdx, maxv);
    k_median<<<BQ, 256, 0, stream>>>(maxv, refCount, threshv, outth);
    k_match<<<dim3(256, BQ), 256, 0, stream>>>(sim, maskc, refCount, refIdx, threshv, match);
}

// Round 7
// 825.546 us; speedup vs baseline: 1.2769x; 1.0246x over previous
//
#include <hip/hip_runtime.h>
#include <hip/hip_bf16.h>
#include <stdint.h>
#include <math.h>

// Problem constants (fixed-shape problem)
#define BQ 4
#define NQ 4096
#define CQ 1024

// ws layout (bytes)
#define WS_CTR      0         // int c123 @0, c3f @4; int refCount[4] @16
#define WS_THRESH   64        // float[4]
#define WS_MASK     256       // uint8[BQ*NQ] = 16384  -> ends 16640
#define WS_REFIDX   17408     // int[BQ*NQ]  = 65536  -> ends 82944
#define WS_MAXV     82944     // float[BQ*NQ]= 65536  -> ends 148480
#define WS_FNH      (4u << 20)               // bf16 hi[BQ*NQ*CQ] = 32 MB
#define WS_FNL      (WS_FNH + (32u << 20))   // bf16 lo[BQ*NQ*CQ] = 32 MB
#define WS_NEED     (WS_FNL + (32u << 20) + (1u << 20))

typedef __bf16 bf16x8 __attribute__((ext_vector_type(8)));
typedef float floatx4 __attribute__((ext_vector_type(4)));

// ---------------------------------------------------------------------------
// K0a: detect mask dtype. Reads only first BQ*NQ bytes (safe under u8/i32/f32).
__global__ void k_detect(const uint8_t* mraw, int* ctr) {
    int c123 = 0, c3f = 0;
    for (int i = threadIdx.x; i < BQ * NQ; i += blockDim.x) {
        uint8_t v = mraw[i];
        int m4 = i & 3;
        if (m4 != 0 && v != 0) c123++;
        if (m4 == 3 && v == 0x3F) c3f++;
    }
    atomicAdd(&ctr[0], c123);
    atomicAdd(&ctr[1], c3f);
}

// K0b: canonicalize mask to uint8 0/1
__global__ void k_canon(const void* mraw, const int* ctr, uint8_t* maskc) {
    int i = blockIdx.x * blockDim.x + threadIdx.x;
    if (i >= BQ * NQ) return;
    int c123 = ctr[0], c3f = ctr[1];
    uint8_t v;
    if (c3f > 64) {
        v = (((const float*)mraw)[i] != 0.0f) ? 1 : 0;
    } else if (c123 == 0) {
        v = (((const int*)mraw)[i] != 0) ? 1 : 0;
    } else {
        v = (((const uint8_t*)mraw)[i] != 0) ? 1 : 0;
    }
    maskc[i] = v;
}

// K0c: compact ref-row indices per batch
__global__ void k_compact(const uint8_t* maskc, int* refCount, int* refIdx) {
    int b = blockIdx.x;
    for (int i = threadIdx.x; i < NQ; i += blockDim.x) {
        if (maskc[b * NQ + i]) {
            int p = atomicAdd(&refCount[b], 1);
            refIdx[b * NQ + p] = i;
        }
    }
}

// K1: fused row norm (f64) + bf16 SPLIT convert: xn = h + l with h = bf16(xn),
// l = bf16(xn - h). h+l represents the f32 normalized value to ~2^-18 rel,
// enabling near-f32-exact Gram via 3 MFMA passes (hh+hl+lh; ll dropped, see K2).
// bf16 (not fp16) keeps l in normal range (bf16 min normal 1.2e-38).
__global__ __launch_bounds__(128) void k_prep(const float* x, __bf16* fnh, __bf16* fnl) {
    int row = blockIdx.x;  // 0..BQ*NQ-1
    int t = threadIdx.x;
    const float4* xr = (const float4*)(x + (long long)row * CQ);
    float4 a = xr[t * 2 + 0];
    float4 c = xr[t * 2 + 1];
    double s = (double)a.x * a.x + (double)a.y * a.y + (double)a.z * a.z + (double)a.w * a.w
             + (double)c.x * c.x + (double)c.y * c.y + (double)c.z * c.z + (double)c.w * c.w;
    __shared__ double red[128];
    __shared__ double invs;
    red[t] = s;
    __syncthreads();
    for (int o = 64; o > 0; o >>= 1) {
        if (t < o) red[t] += red[t + o];
        __syncthreads();
    }
    if (t == 0) invs = 1.0 / fmax(sqrt(red[0]), 1e-12);
    __syncthreads();
    float ir = (float)invs;
    float v[8] = {a.x, a.y, a.z, a.w, c.x, c.y, c.z, c.w};
    bf16x8 h8, l8;
#pragma unroll
    for (int j = 0; j < 8; j++) {
        float xn = v[j] * ir;
        __bf16 h = (__bf16)xn;
        h8[j] = h;
        l8[j] = (__bf16)(xn - (float)h);
    }
    *(bf16x8*)(fnh + (long long)row * CQ + t * 8) = h8;
    *(bf16x8*)(fnl + (long long)row * CQ + t * 8) = l8;
}

// K2: uniform split-bf16 MFMA Gram GEMM, upper-tri 128x128 tiles.
//   sim = (h_r+l_r)·(h_c+l_c) ≈ hh + hl + lh via 3 chained MFMA passes into a
//   single f32 accumulator. R6: the ll pass is DROPPED — |Σ l_i l_j| ≤
//   ||l_r||·||l_c|| ≤ 2^-18 ≈ 3.8e-6 worst-case (typ ~1e-7), two orders below
//   the observed 4.9e-4 absmax floor. Saves 25% of MFMA work (64->48 per
//   wave-k-step; machine floor 114 -> 86 µs). LDS staging unchanged (Al still
//   needed for lh, Bl for hl).
// XCD swizzle: 2112 blocks = 8 x 264 (bijective); consecutive gids share the
// same rT A-panel (512 KB h+l) -> per-XCD L2 reuse.
// LDS swizzle (T2/rule #21): unchanged from R1 (verified): linear LDS dest,
// pre-swizzled global source col, same XOR on the read.
#define GRID_MEGA 2112
__global__ __launch_bounds__(256) void k_mega(const __bf16* fnh, const __bf16* fnl,
                                              float* sim, float* match) {
    __shared__ __align__(16) char smem[32768];
    const int id = blockIdx.x;
    const int gid = (id & 7) * 264 + (id >> 3);   // XCD-contiguous tri order
    const int b = gid / 528;
    int rem = gid % 528;
    int rT = 0;
    while (rem >= 32 - rT) { rem -= 32 - rT; rT++; }
    const int cT = rT + rem;
    const int rowBase = rT * 128;
    const int colBase = cT * 128;
    const __bf16* baseh = fnh + (long long)b * NQ * CQ;
    const __bf16* basel = fnl + (long long)b * NQ * CQ;
    __bf16* smAh = (__bf16*)smem;               // 128*32*2 = 8192 B each
    __bf16* smAl = (__bf16*)(smem + 8192);
    __bf16* smBh = (__bf16*)(smem + 16384);
    __bf16* smBl = (__bf16*)(smem + 24576);

    const int lane = threadIdx.x & 63;
    const int w = threadIdx.x >> 6;
    const int wr = w >> 1, wc = w & 1;
    const int ldrow = lane >> 2;
    // stage-side swizzled source col (elems): ((lane&3)*8) ^ swz(row), row%16 = lane>>2
    const int ldcolS = ((lane & 3) * 8) ^ (((lane >> 3) & 3) << 3);
    // read-side swizzled col (elems): ((lane>>4)*8) ^ swz(row), row%16 = lane&15
    const int co = ((lane >> 4) * 8) ^ (((lane >> 1) & 3) << 3);

    floatx4 acc[4][4] = {};

    for (int k0 = 0; k0 < CQ; k0 += 32) {
        __syncthreads();
#pragma unroll
        for (int i = 0; i < 2; i++) {
            int rsub = w * 16 + i * 64;
            long long offA = (long long)(rowBase + rsub + ldrow) * CQ + k0 + ldcolS;
            long long offB = (long long)(colBase + rsub + ldrow) * CQ + k0 + ldcolS;
            __builtin_amdgcn_global_load_lds(
                (const __attribute__((address_space(1))) void*)(baseh + offA),
                (__attribute__((address_space(3))) void*)(smAh + rsub * 32), 16, 0, 0);
            __builtin_amdgcn_global_load_lds(
                (const __attribute__((address_space(1))) void*)(basel + offA),
                (__attribute__((address_space(3))) void*)(smAl + rsub * 32), 16, 0, 0);
            __builtin_amdgcn_global_load_lds(
                (const __attribute__((address_space(1))) void*)(baseh + offB),
                (__attribute__((address_space(3))) void*)(smBh + rsub * 32), 16, 0, 0);
            __builtin_amdgcn_global_load_lds(
                (const __attribute__((address_space(1))) void*)(basel + offB),
                (__attribute__((address_space(3))) void*)(smBl + rsub * 32), 16, 0, 0);
        }
        __syncthreads();

        bf16x8 ah[4], al[4];
#pragma unroll
        for (int i = 0; i < 4; i++) {
            int ra = (wr * 64 + i * 16 + (lane & 15)) * 32 + co;
            ah[i] = *(const bf16x8*)(smAh + ra);
            al[i] = *(const bf16x8*)(smAl + ra);
        }
#pragma unroll
        for (int j = 0; j < 4; j++) {
            int rb = (wc * 64 + j * 16 + (lane & 15)) * 32 + co;
            bf16x8 bh = *(const bf16x8*)(smBh + rb);
            bf16x8 bl = *(const bf16x8*)(smBl + rb);
#pragma unroll
            for (int i = 0; i < 4; i++) {
                acc[i][j] = __builtin_amdgcn_mfma_f32_16x16x32_bf16(ah[i], bh, acc[i][j], 0, 0, 0);
                acc[i][j] = __builtin_amdgcn_mfma_f32_16x16x32_bf16(ah[i], bl, acc[i][j], 0, 0, 0);
                acc[i][j] = __builtin_amdgcn_mfma_f32_16x16x32_bf16(al[i], bh, acc[i][j], 0, 0, 0);
            }
        }
    }

    // Epilogue A: own tile (rT,cT): sim values + match zeros, all rows.
    float* simb = sim + (long long)b * NQ * NQ;
    float* matb = match + (long long)b * NQ * NQ;
#pragma unroll
    for (int i = 0; i < 4; i++) {
        int r0 = rowBase + wr * 64 + i * 16 + (lane >> 4) * 4;
#pragma unroll
        for (int r = 0; r < 4; r++) {
#pragma unroll
            for (int j = 0; j < 4; j++) {
                int c = colBase + wc * 64 + j * 16 + (lane & 15);
                simb[(long long)(r0 + r) * NQ + c] = acc[i][j][r];
                matb[(long long)(r0 + r) * NQ + c] = 0.0f;
            }
        }
    }
    // Epilogue B: mirror tile (cT,rT) for off-diagonal blocks (bit-identical
    // by operand symmetry: hh, hl+lh are each symmetric under i<->j).
    // float4 at (c*NQ + r0), 16B aligned.
    if (rT != cT) {
        floatx4 zero4 = {0.0f, 0.0f, 0.0f, 0.0f};
#pragma unroll
        for (int i = 0; i < 4; i++) {
            int r0 = rowBase + wr * 64 + i * 16 + (lane >> 4) * 4;
#pragma unroll
            for (int j = 0; j < 4; j++) {
                int c = colBase + wc * 64 + j * 16 + (lane & 15);
                long long off = (long long)c * NQ + r0;
                *(floatx4*)(simb + off) = acc[i][j];
                *(floatx4*)(matb + off) = zero4;
            }
        }
    }
}

// K3: per ref slot, max over non-ref cols (slot-based, no wasted blocks)
__global__ __launch_bounds__(256) void k_rowmax(const float* sim, const uint8_t* maskc,
                                                const int* refCount, const int* refIdx,
                                                float* maxv) {
    int b = blockIdx.y;
    int cnt = refCount[b];
    __shared__ float red[256];
    for (int slot = blockIdx.x; slot < cnt; slot += gridDim.x) {
        int row = refIdx[b * NQ + slot];
        const float* rp = sim + ((long long)b * NQ + row) * NQ;
        float mx = -INFINITY;
        for (int j = threadIdx.x; j < NQ; j += 256) {
            if (!maskc[b * NQ + j]) mx = fmaxf(mx, rp[j]);
        }
        __syncthreads();
        red[threadIdx.x] = mx;
        __syncthreads();
        for (int o = 128; o > 0; o >>= 1) {
            if (threadIdx.x < o) red[threadIdx.x] = fmaxf(red[threadIdx.x], red[threadIdx.x + o]);
            __syncthreads();
        }
        if (threadIdx.x == 0) maxv[b * NQ + slot] = red[0];
    }
}

// K4: lower median over slots [0,cnt) per batch (O(k^2) rank counting)
__global__ __launch_bounds__(256) void k_median(const float* maxv, const int* refCount,
                                                float* threshv, float* outth) {
    int b = blockIdx.x;
    int k = refCount[b];
    __shared__ float vals[NQ];
    __shared__ float result;
    for (int i = threadIdx.x; i < k; i += blockDim.x) vals[i] = maxv[b * NQ + i];
    __syncthreads();
    int med = (k - 1) / 2;
    for (int t0 = threadIdx.x; t0 < k; t0 += blockDim.x) {
        float v = vals[t0];
        int cl = 0, ce = 0;
        for (int j = 0; j < k; j++) {
            float w = vals[j];
            cl += (w < v) ? 1 : 0;
            ce += (w == v) ? 1 : 0;
        }
        if (cl <= med && med < cl + ce) result = v;  // unique value class; benign race
    }
    __syncthreads();
    if (threadIdx.x == 0) {
        threshv[b] = result;
        outth[b] = result;
    }
}

// K5: match bits for ref rows (background zeros already written by k_mega)
__global__ __launch_bounds__(256) void k_match(const float* sim, const uint8_t* maskc,
                                               const int* refCount, const int* refIdx,
                                               const float* threshv, float* match) {
    int b = blockIdx.y;
    int cnt = refCount[b];
    float th = threshv[b];
    const uint8_t* mb = maskc + b * NQ;
    for (int slot = blockIdx.x; slot < cnt; slot += gridDim.x) {
        int row = refIdx[b * NQ + slot];
        const float* rp = sim + ((long long)b * NQ + row) * NQ;
        float* op = match + ((long long)b * NQ + row) * NQ;
        for (int j = threadIdx.x * 4; j < NQ; j += 256 * 4) {
            float4 s = *(const float4*)(rp + j);
            float4 o;
            o.x = (!mb[j + 0] && s.x > th) ? 1.0f : 0.0f;
            o.y = (!mb[j + 1] && s.y > th) ? 1.0f : 0.0f;
            o.z = (!mb[j + 2] && s.z > th) ? 1.0f : 0.0f;
            o.w = (!mb[j + 3] && s.w > th) ? 1.0f : 0.0f;
            *(float4*)(op + j) = o;
        }
    }
}

extern "C" void kernel_launch(void* const* d_in, const int* in_sizes, int n_in,
                              void* d_out, int out_size, void* d_ws, size_t ws_size,
                              hipStream_t stream) {
    if (in_sizes[0] != BQ * NQ * CQ) return;
    if (ws_size < WS_NEED) return;  // d_ws observed ~2 GiB (poison fills)

    const float* x = (const float*)d_in[0];
    const void* mraw = d_in[1];
    float* out = (float*)d_out;
    uint8_t* ws = (uint8_t*)d_ws;

    int* ctr       = (int*)(ws + WS_CTR);
    int* refCount  = (int*)(ws + 16);
    float* threshv = (float*)(ws + WS_THRESH);
    uint8_t* maskc = ws + WS_MASK;
    int* refIdx    = (int*)(ws + WS_REFIDX);
    float* maxv    = (float*)(ws + WS_MAXV);
    __bf16* fnh    = (__bf16*)(ws + WS_FNH);
    __bf16* fnl    = (__bf16*)(ws + WS_FNL);

    float* match = out;                                // [B,N,N] as 0/1 floats
    float* sim   = out + (long long)BQ * NQ * NQ;      // [B,N,N]
    float* outth = out + 2LL * BQ * NQ * NQ;           // [B]

    hipMemsetAsync(ws, 0, 4096, stream);  // counters

    k_detect<<<1, 256, 0, stream>>>((const uint8_t*)mraw, ctr);
    k_canon<<<(BQ * NQ + 255) / 256, 256, 0, stream>>>(mraw, ctr, maskc);
    k_compact<<<BQ, 256, 0, stream>>>(maskc, refCount, refIdx);
    k_prep<<<BQ * NQ, 128, 0, stream>>>(x, fnh, fnl);
    k_mega<<<GRID_MEGA, 256, 0, stream>>>(fnh, fnl, sim, match);
    k_rowmax<<<dim3(256, BQ), 256, 0, stream>>>(sim, maskc, refCount, refIdx, maxv);
    k_median<<<BQ, 256, 0, stream>>>(maxv, refCount, threshv, outth);
    k_match<<<dim3(256, BQ), 256, 0, stream>>>(sim, maskc, refCount, refIdx, threshv, match);
}